// Round 7
// baseline (1438.577 us; speedup 1.0000x reference)
//
#include <hip/hip_runtime.h>

#define N_NODES 50000
#define N_EDGES 640000
#define HDIM    128
#define NLAYERS 3

typedef __attribute__((ext_vector_type(4))) float f32x4;
typedef short s16x8 __attribute__((ext_vector_type(8)));
typedef __bf16 bf16v8 __attribute__((ext_vector_type(8)));

static __device__ __forceinline__ unsigned short f2b(float f){
  unsigned int u = __float_as_uint(f);
  unsigned int r = u + 0x7FFFu + ((u >> 16) & 1u);
  return (unsigned short)(r >> 16);
}
static __device__ __forceinline__ float b2f(unsigned short h){
  return __uint_as_float(((unsigned int)h) << 16);
}
static __device__ __forceinline__ float silu_f(float x){
  return x / (1.0f + __expf(-x));
}
static __device__ __forceinline__ unsigned int cvt2(float a, float b){
  unsigned int r;
  asm("v_cvt_pk_bf16_f32 %0, %1, %2" : "=v"(r) : "v"(a), "v"(b));
  return r;
}
static __device__ __forceinline__ s16x8 siluPack(const f32x4 a, const f32x4 b){
  union { unsigned int u[4]; s16x8 v; } r;
  r.u[0] = cvt2(silu_f(a[0]), silu_f(a[1]));
  r.u[1] = cvt2(silu_f(a[2]), silu_f(a[3]));
  r.u[2] = cvt2(silu_f(b[0]), silu_f(b[1]));
  r.u[3] = cvt2(silu_f(b[2]), silu_f(b[3]));
  return r.v;
}
static __device__ __forceinline__ f32x4 MFMA(s16x8 a, s16x8 b, f32x4 c){
  return __builtin_amdgcn_mfma_f32_16x16x32_bf16(
      __builtin_bit_cast(bf16v8, a), __builtin_bit_cast(bf16v8, b), c, 0, 0, 0);
}

// A-fragment from global (node/embed kernels): WT[out][K] row-major
static __device__ __forceinline__ s16x8 ldA(const unsigned short* __restrict__ WT,
                                            int K, int s, int kk, int lane){
  const unsigned short* p = WT + (size_t)((s<<4) + (lane&15))*K + (kk<<5) + ((lane>>4)<<2);
  ushort4 a = *(const ushort4*)p;
  ushort4 b = *(const ushort4*)(p + 16);
  s16x8 r;
  r[0]=(short)a.x; r[1]=(short)a.y; r[2]=(short)a.z; r[3]=(short)a.w;
  r[4]=(short)b.x; r[5]=(short)b.y; r[6]=(short)b.z; r[7]=(short)b.w;
  return r;
}
static __device__ __forceinline__ s16x8 ldBf32(const float* __restrict__ p, int q){
  float4 a = *(const float4*)(p + (q<<2));
  float4 b = *(const float4*)(p + 16 + (q<<2));
  s16x8 r;
  r[0]=(short)f2b(a.x); r[1]=(short)f2b(a.y); r[2]=(short)f2b(a.z); r[3]=(short)f2b(a.w);
  r[4]=(short)f2b(b.x); r[5]=(short)f2b(b.y); r[6]=(short)f2b(b.z); r[7]=(short)f2b(b.w);
  return r;
}

#define GLL(SRC, DST) __builtin_amdgcn_global_load_lds( \
    (const __attribute__((address_space(1))) void*)(SRC), \
    (__attribute__((address_space(3))) void*)(DST), 16, 0, 0)

// ---------------- fused weight transposes (8 jobs, 1 launch) ----------------
struct ConvJob { const float* src; unsigned short* dst; int kshift; };
struct ConvJobs { ConvJob j[8]; };
__global__ void k_conv8(ConvJobs jobs){
  const ConvJob jb = jobs.j[blockIdx.y];
  const int K = 1 << jb.kshift;
  const int idx = (blockIdx.x<<8) + threadIdx.x;
  if (idx < (K<<7)){
    const int n = idx >> jb.kshift;
    const int k = idx & (K-1);
    jb.dst[idx] = f2b(jb.src[(size_t)k*HDIM + n]);
  }
}

// blob: 16 tiles of 4096 bf16. t=0..7: W1 (K=256); 8..11: W2; 12..15: W3.
// elem i: n=(i>>5)&127, slot=(i>>3)&3, j=i&7; q=slot^((n>>1)&3);
// kl=((j>>2)<<4)+(q<<2)+(j&3)
struct BlobJob { const float *W1, *W2, *W3; unsigned short* dst; };
struct BlobJobs { BlobJob j[4]; };
__global__ void k_blob4(BlobJobs jobs){
  const BlobJob jb = jobs.j[blockIdx.y];
  const int i = (blockIdx.x<<8) + threadIdx.x;   // < 65536
  const int t = i >> 12;
  const int n = (i >> 5) & 127;
  const int slot = (i >> 3) & 3;
  const int j = i & 7;
  const int q = slot ^ ((n >> 1) & 3);
  const int kl = ((j >> 2) << 4) + (q << 2) + (j & 3);
  float v;
  if (t < 8)       v = jb.W1[(size_t)((t<<5)+kl)*HDIM + n];
  else if (t < 12) v = jb.W2[(size_t)(((t-8)<<5)+kl)*HDIM + n];
  else             v = jb.W3[(size_t)(((t-12)<<5)+kl)*HDIM + n];
  jb.dst[i] = f2b(v);
}

// ---------------- fused init: zero degi/cu/epsb + copy x ----------------
__global__ void k_init(const float* __restrict__ xin, float* __restrict__ xbuf,
                       float* __restrict__ cu, float* __restrict__ epsb,
                       int* __restrict__ degi){
  const int i = (blockIdx.x<<8) + threadIdx.x;
  if (i < N_NODES*3){ xbuf[i] = xin[i]; cu[i] = 0.f; epsb[i] = 0.f; }
  if (i < N_NODES) degi[i] = 0;
}

// ---------------- CSR build ----------------
__global__ void k_degree(const int* __restrict__ coli, int* __restrict__ degi){
  const int e = (blockIdx.x<<8) + threadIdx.x;
  if (e < N_EDGES) atomicAdd(&degi[coli[e]], 1);
}
__global__ void k_scanA(const int* __restrict__ degi, int* __restrict__ off, int* __restrict__ bsum){
  const int t = threadIdx.x, b = blockIdx.x;
  const int i = (b<<8) + t;
  const int v = (i < N_NODES) ? degi[i] : 0;
  int x = v;
  const int lane = t & 63;
  #pragma unroll
  for (int d=1; d<64; d<<=1){ int y = __shfl_up(x, d); if (lane >= d) x += y; }
  __shared__ int wsum[4];
  if (lane == 63) wsum[t>>6] = x;
  __syncthreads();
  int wo = 0;
  #pragma unroll
  for (int w=0; w<4; ++w) if (w < (t>>6)) wo += wsum[w];
  const int incl = x + wo;
  if (i < N_NODES) off[i] = incl - v;
  if (t == 255) bsum[b] = incl;
}
__global__ void k_scanB(int* __restrict__ bsum, int nb){
  const int t = threadIdx.x;
  const int v = (t < nb) ? bsum[t] : 0;
  int x = v;
  const int lane = t & 63;
  #pragma unroll
  for (int d=1; d<64; d<<=1){ int y = __shfl_up(x, d); if (lane >= d) x += y; }
  __shared__ int wsum[4];
  if (lane == 63) wsum[t>>6] = x;
  __syncthreads();
  int wo = 0;
  #pragma unroll
  for (int w=0; w<4; ++w) if (w < (t>>6)) wo += wsum[w];
  const int incl = x + wo;
  if (t < nb) bsum[t] = incl - v;
}
__global__ void k_scanC(int* __restrict__ off, const int* __restrict__ bsum, int* __restrict__ cursor){
  const int i = (blockIdx.x<<8) + threadIdx.x;
  if (i < N_NODES){
    const int o = off[i] + bsum[i>>8];
    off[i] = o;
    cursor[i] = o;
  }
}
__global__ void k_fill(const int* __restrict__ coli, int* __restrict__ cursor, int* __restrict__ perm){
  const int e = (blockIdx.x<<8) + threadIdx.x;
  if (e < N_EDGES){
    const int p = atomicAdd(&cursor[coli[e]], 1);
    perm[e] = p;
  }
}

// ---------------- embedding: h = h_in @ W_emb + b_emb (+ bf16 mirror) --------
__global__ __launch_bounds__(256) void k_embed(
    const float* __restrict__ hin, const unsigned short* __restrict__ WembT,
    const float* __restrict__ bemb, float* __restrict__ hbuf,
    unsigned short* __restrict__ hb)
{
  __shared__ float s_b[128];
  const int tid = threadIdx.x;
  if (tid < 128) s_b[tid] = bemb[tid];
  __syncthreads();
  const int lane = tid & 63, q = lane>>4;
  const int n = (blockIdx.x<<6) + ((tid>>6)<<4) + (lane&15);
  const bool valid = n < N_NODES;
  const int nc = valid ? n : (N_NODES-1);
  const float* __restrict__ hp = hin + (size_t)nc*64;
  f32x4 acc[8];
  #pragma unroll
  for (int s=0;s<8;++s)
    #pragma unroll
    for (int r=0;r<4;++r) acc[s][r] = s_b[(s<<4)+(q<<2)+r];
  #pragma unroll
  for (int kk=0;kk<2;++kk){
    const s16x8 bf = ldBf32(hp + (kk<<5), q);
    #pragma unroll
    for (int s=0;s<8;++s) acc[s] = MFMA(ldA(WembT, 64, s, kk, lane), bf, acc[s]);
  }
  if (valid){
    float* op = hbuf + (size_t)n*HDIM;
    unsigned short* hbw = hb + (size_t)n*HDIM;
    #pragma unroll
    for (int s=0;s<8;++s){
      float4 o; o.x=acc[s][0]; o.y=acc[s][1]; o.z=acc[s][2]; o.w=acc[s][3];
      *(float4*)(op + (s<<4) + (q<<2)) = o;
      ushort4 u; u.x=f2b(o.x); u.y=f2b(o.y); u.z=f2b(o.z); u.w=f2b(o.w);
      *(ushort4*)(hbw + ((s>>1)<<5) + (q<<3) + ((s&1)<<2)) = u;
    }
  }
}

// ------- per-layer edge MLP: whole-blob LDS-resident, barrier-free ----------
// 512 threads, 2 edges/thread, 256 edges/block, 2500 blocks.
// Live set fits the 128-VGPR budget the RA enforces -> no spills.
template<bool CSR>
__global__ __launch_bounds__(512,2) void k_edge_mlp(
    const unsigned short* __restrict__ hb, const float* __restrict__ xbuf,
    const int* __restrict__ rowi, const int* __restrict__ coli,
    const int* __restrict__ perm, const unsigned short* __restrict__ blob,
    const float* __restrict__ bm1v, const float* __restrict__ wm1r,
    const float* __restrict__ bm2v, const float* __restrict__ bc1v,
    const float* __restrict__ wc2v,
    unsigned short* __restrict__ m_buf, float* __restrict__ agg,
    float* __restrict__ cu)
{
  __shared__ struct {
    __align__(16) unsigned char wbuf[16][8192];   // 128 KiB weights
    int pmS[256];
    float rdS[3][256];
  } sm;
  const int tid = threadIdx.x, lane = tid & 63, q = lane >> 4;
  const int w = tid >> 6;
  const int q8 = q << 3;
  const int ebase = blockIdx.x << 8;

  // stage entire blob once: 16B per tile per thread (linear, lane*16 dest)
  #pragma unroll
  for (int t=0;t<16;++t)
    GLL(blob + (t<<12) + (tid<<3), &sm.wbuf[t][tid<<4]);

  int rn[2], cn[2];
  float dist[2];
  #pragma unroll
  for (int e=0;e<2;++e){
    const int el = (w<<5) + (e<<4) + (lane&15);
    const int ge = ebase + el;
    rn[e] = rowi[ge]; cn[e] = coli[ge];
    const float dx = xbuf[3*rn[e]+0] - xbuf[3*cn[e]+0];
    const float dy = xbuf[3*rn[e]+1] - xbuf[3*cn[e]+1];
    const float dz = xbuf[3*rn[e]+2] - xbuf[3*cn[e]+2];
    const float d = sqrtf(dx*dx + dy*dy + dz*dz);
    dist[e] = d;
    if (q == 0){
      const float inv = 1.0f / (d + 1e-8f);
      sm.rdS[0][el] = dx*inv; sm.rdS[1][el] = dy*inv; sm.rdS[2][el] = dz*inv;
      if (CSR) sm.pmS[el] = perm[ge];
    }
  }

  // GEMM1 acc init: bias + dist*W[256] row in fp32
  f32x4 acc[2][8];
  #pragma unroll
  for (int s=0;s<8;++s){
    const f32x4 b1 = *(const f32x4*)&bm1v[(s<<4)+(q<<2)];
    const f32x4 wv = *(const f32x4*)&wm1r[(s<<4)+(q<<2)];
    #pragma unroll
    for (int e=0;e<2;++e)
      #pragma unroll
      for (int r=0;r<4;++r) acc[e][s][r] = b1[r] + dist[e]*wv[r];
  }
  const int toff = ((lane&15)<<6) + ((q ^ ((lane>>1)&3))<<4);

  // depth-2 B prefetch pipeline
  s16x8 B0[2], B1[2];
  #pragma unroll
  for (int e=0;e<2;++e){
    B0[e] = *(const s16x8*)(hb + ((size_t)rn[e]<<7) + q8);          // kk0
    B1[e] = *(const s16x8*)(hb + ((size_t)rn[e]<<7) + 32 + q8);     // kk1
  }

  __syncthreads();   // drains staging + metadata LDS writes; only barrier

  // GEMM1: K=256 over tiles 0..7
  #pragma unroll
  for (int kk=0;kk<8;++kk){
    s16x8 Bn[2];
    if (kk < 6){
      const int k2 = kk+2;
      #pragma unroll
      for (int e=0;e<2;++e){
        const int node = (k2 < 4) ? rn[e] : cn[e];
        Bn[e] = *(const s16x8*)(hb + ((size_t)node<<7) + ((k2&3)<<5) + q8);
      }
    }
    #pragma unroll
    for (int s=0;s<8;++s){
      const s16x8 A = *(const s16x8*)&sm.wbuf[kk][(s<<10)+toff];
      #pragma unroll
      for (int e=0;e<2;++e) acc[e][s] = MFMA(A, B0[e], acc[e][s]);
    }
    #pragma unroll
    for (int e=0;e<2;++e){ B0[e] = B1[e]; if (kk < 6) B1[e] = Bn[e]; }
  }

  s16x8 sb[2][4];
  #pragma unroll
  for (int e=0;e<2;++e)
    #pragma unroll
    for (int c=0;c<4;++c) sb[e][c] = siluPack(acc[e][2*c], acc[e][2*c+1]);

  f32x4 acc2[2][8];
  #pragma unroll
  for (int s=0;s<8;++s){
    const f32x4 b = *(const f32x4*)&bm2v[(s<<4)+(q<<2)];
    #pragma unroll
    for (int e=0;e<2;++e) acc2[e][s] = b;
  }
  #pragma unroll
  for (int c=0;c<4;++c)
    #pragma unroll
    for (int s=0;s<8;++s){
      const s16x8 A = *(const s16x8*)&sm.wbuf[8+c][(s<<10)+toff];
      #pragma unroll
      for (int e=0;e<2;++e) acc2[e][s] = MFMA(A, sb[e][c], acc2[e][s]);
    }

  s16x8 mb[2][4];
  #pragma unroll
  for (int e=0;e<2;++e)
    #pragma unroll
    for (int c=0;c<4;++c) mb[e][c] = siluPack(acc2[e][2*c], acc2[e][2*c+1]);

  f32x4 acc3[2][8];
  #pragma unroll
  for (int s=0;s<8;++s){
    const f32x4 b = *(const f32x4*)&bc1v[(s<<4)+(q<<2)];
    #pragma unroll
    for (int e=0;e<2;++e) acc3[e][s] = b;
  }
  #pragma unroll
  for (int c=0;c<4;++c)
    #pragma unroll
    for (int s=0;s<8;++s){
      const s16x8 A = *(const s16x8*)&sm.wbuf[12+c][(s<<10)+toff];
      #pragma unroll
      for (int e=0;e<2;++e) acc3[e][s] = MFMA(A, mb[e][c], acc3[e][s]);
    }

  // epilogue: coord scatter + m store
  float dot[2] = {0.f,0.f};
  #pragma unroll
  for (int s=0;s<8;++s){
    const f32x4 wv = *(const f32x4*)&wc2v[(s<<4)+(q<<2)];
    #pragma unroll
    for (int e=0;e<2;++e)
      #pragma unroll
      for (int r=0;r<4;++r) dot[e] += silu_f(acc3[e][s][r]) * wv[r];
  }
  #pragma unroll
  for (int e=0;e<2;++e){
    dot[e] += __shfl_xor(dot[e], 16);
    dot[e] += __shfl_xor(dot[e], 32);
    const float cm = tanhf(dot[e]);
    const int el = (w<<5) + (e<<4) + (lane&15);
    if (q < 3)
      atomicAdd(&cu[(size_t)cn[e]*3 + q], cm * sm.rdS[q][el]);
  }
  if (CSR){
    #pragma unroll
    for (int e=0;e<2;++e){
      const int el = (w<<5) + (e<<4) + (lane&15);
      unsigned short* mp = m_buf + ((size_t)sm.pmS[el]<<7) + q8;
      #pragma unroll
      for (int c=0;c<4;++c) *(s16x8*)(mp + (c<<5)) = mb[e][c];
    }
  } else {
    #pragma unroll
    for (int e=0;e<2;++e){
      float* ap = agg + (size_t)cn[e]*HDIM + (q<<2);
      #pragma unroll
      for (int c=0;c<4;++c)
        #pragma unroll
        for (int j=0;j<8;++j){
          const int o = (((c<<1)+(j>>2))<<4) + (j&3);
          atomicAdd(ap + o, b2f((unsigned short)mb[e][c][j]));
        }
    }
  }
}

// ---------------- per-layer node update (sequential m_buf; zeroes cu) --------
template<bool CSR>
__global__ __launch_bounds__(256) void k_node_mlp(
    float* __restrict__ hbuf, unsigned short* __restrict__ hb,
    float* __restrict__ xbuf,
    const unsigned short* __restrict__ m_buf, const float* __restrict__ agg,
    const int* __restrict__ off, const int* __restrict__ degi,
    float* __restrict__ cu,
    const unsigned short* __restrict__ Wn1T, const float* __restrict__ bn1v,
    const unsigned short* __restrict__ Wn2T, const float* __restrict__ bn2v,
    const float* __restrict__ lng, const float* __restrict__ lnb)
{
  __shared__ float s_bn1[128], s_bn2[128], s_g[128], s_b[128];
  const int tid = threadIdx.x;
  const int nbase = blockIdx.x << 6;
  if (tid >= 128){
    const int f = tid - 128;
    s_bn1[f]=bn1v[f]; s_bn2[f]=bn2v[f]; s_g[f]=lng[f]; s_b[f]=lnb[f];
  } else if (tid < 64){
    const int n = nbase + tid;
    if (n < N_NODES){
      const float dd = (float)degi[n] + 1.0f;
      #pragma unroll
      for (int c=0;c<3;++c){
        xbuf[3*n+c] += cu[3*n+c] / dd;
        cu[3*n+c] = 0.f;                 // ready for next layer
      }
    }
  }
  __syncthreads();

  const int lane = tid & 63, q = lane >> 4;
  const int q8 = q << 3;
  const int n = nbase + ((tid>>6)<<4) + (lane & 15);
  const bool valid = (n < N_NODES);
  const int nc = valid ? n : (N_NODES-1);
  const float* __restrict__ hp = hbuf + (size_t)nc*HDIM;
  const unsigned short* __restrict__ hbp = hb + (size_t)nc*HDIM;

  float aggv[4][8];
  #pragma unroll
  for (int kk=0;kk<4;++kk)
    #pragma unroll
    for (int j=0;j<8;++j) aggv[kk][j]=0.f;
  if (CSR){
    const int st = off[nc];
    const int cnt = degi[nc];
    for (int ii=0; ii<cnt; ++ii){
      const unsigned short* mrow = m_buf + ((size_t)(st+ii)<<7);
      #pragma unroll
      for (int kk=0;kk<4;++kk){
        const s16x8 v = *(const s16x8*)(mrow + (kk<<5) + q8);
        #pragma unroll
        for (int j=0;j<8;++j) aggv[kk][j] += b2f((unsigned short)v[j]);
      }
    }
  } else {
    const float* ap = agg + (size_t)nc*HDIM;
    #pragma unroll
    for (int kk=0;kk<4;++kk){
      float4 a = *(const float4*)(ap + (kk<<5) + (q<<2));
      float4 b = *(const float4*)(ap + (kk<<5) + 16 + (q<<2));
      aggv[kk][0]=a.x; aggv[kk][1]=a.y; aggv[kk][2]=a.z; aggv[kk][3]=a.w;
      aggv[kk][4]=b.x; aggv[kk][5]=b.y; aggv[kk][6]=b.z; aggv[kk][7]=b.w;
    }
  }

  f32x4 acc[8];
  #pragma unroll
  for (int s=0;s<8;++s)
    #pragma unroll
    for (int r=0;r<4;++r) acc[s][r] = s_bn1[(s<<4)+(q<<2)+r];
  #pragma unroll
  for (int kk=0;kk<4;++kk){
    const s16x8 bf = *(const s16x8*)(hbp + (kk<<5) + q8);
    #pragma unroll
    for (int s=0;s<8;++s) acc[s] = MFMA(ldA(Wn1T, 256, s, kk, lane), bf, acc[s]);
  }
  #pragma unroll
  for (int kk=0;kk<4;++kk){
    s16x8 bf;
    #pragma unroll
    for (int j=0;j<8;++j) bf[j] = (short)f2b(aggv[kk][j]);
    #pragma unroll
    for (int s=0;s<8;++s) acc[s] = MFMA(ldA(Wn1T, 256, s, kk+4, lane), bf, acc[s]);
  }
  s16x8 sb[4];
  #pragma unroll
  for (int t=0;t<4;++t)
    #pragma unroll
    for (int j=0;j<8;++j)
      sb[t][j] = (short)f2b(silu_f(acc[(t<<1)+(j>>2)][j&3]));
  f32x4 acc2[8];
  #pragma unroll
  for (int s=0;s<8;++s)
    #pragma unroll
    for (int r=0;r<4;++r) acc2[s][r] = s_bn2[(s<<4)+(q<<2)+r];
  #pragma unroll
  for (int kk=0;kk<4;++kk){
    #pragma unroll
    for (int s=0;s<8;++s) acc2[s] = MFMA(ldA(Wn2T, 128, s, kk, lane), sb[kk], acc2[s]);
  }

  float v[8][4];
  float sum = 0.f;
  #pragma unroll
  for (int s=0;s<8;++s){
    float4 h4 = *(const float4*)(hp + (s<<4) + (q<<2));
    v[s][0] = h4.x + acc2[s][0]; v[s][1] = h4.y + acc2[s][1];
    v[s][2] = h4.z + acc2[s][2]; v[s][3] = h4.w + acc2[s][3];
    sum += v[s][0]+v[s][1]+v[s][2]+v[s][3];
  }
  sum += __shfl_xor(sum, 16);
  sum += __shfl_xor(sum, 32);
  const float mu = sum * (1.0f/128.0f);
  float vs = 0.f;
  #pragma unroll
  for (int s=0;s<8;++s)
    #pragma unroll
    for (int r=0;r<4;++r){ const float d = v[s][r]-mu; vs += d*d; }
  vs += __shfl_xor(vs, 16);
  vs += __shfl_xor(vs, 32);
  const float rs = rsqrtf(vs*(1.0f/128.0f) + 1e-5f);
  if (valid){
    float* op = hbuf + (size_t)n*HDIM;
    unsigned short* hbw = hb + (size_t)n*HDIM;
    #pragma unroll
    for (int s=0;s<8;++s){
      const int f0 = (s<<4)+(q<<2);
      float4 o;
      o.x = (v[s][0]-mu)*rs*s_g[f0+0] + s_b[f0+0];
      o.y = (v[s][1]-mu)*rs*s_g[f0+1] + s_b[f0+1];
      o.z = (v[s][2]-mu)*rs*s_g[f0+2] + s_b[f0+2];
      o.w = (v[s][3]-mu)*rs*s_g[f0+3] + s_b[f0+3];
      *(float4*)(op + f0) = o;
      ushort4 u; u.x=f2b(o.x); u.y=f2b(o.y); u.z=f2b(o.z); u.w=f2b(o.w);
      *(ushort4*)(hbw + ((s>>1)<<5) + q8 + ((s&1)<<2)) = u;
    }
  }
}

// ---------------- epsilon head: edge part (2 edges/thread) ----------------
__global__ __launch_bounds__(512,2) void k_eps_edge(
    const unsigned short* __restrict__ hb, const float* __restrict__ xbuf,
    const int* __restrict__ rowi, const int* __restrict__ coli,
    const unsigned short* __restrict__ blob,
    const float* __restrict__ bem1v, const float* __restrict__ wem_rows,
    const float* __restrict__ bem2v, const float* __restrict__ bec1v,
    const float* __restrict__ Wec2, const float* __restrict__ bec2,
    float* __restrict__ epsb)
{
  __shared__ struct {
    __align__(16) unsigned char wbuf[16][8192];
    float wcs[3][128];
  } sm;
  const int tid = threadIdx.x, lane = tid & 63, q = lane >> 4;
  const int w = tid >> 6;
  const int q8 = q << 3;
  const int ebase = blockIdx.x << 8;

  #pragma unroll
  for (int t=0;t<16;++t)
    GLL(blob + (t<<12) + (tid<<3), &sm.wbuf[t][tid<<4]);
  if (tid < 128){
    sm.wcs[0][tid] = Wec2[tid*3+0];
    sm.wcs[1][tid] = Wec2[tid*3+1];
    sm.wcs[2][tid] = Wec2[tid*3+2];
  }

  int rn[2], cn[2];
  float rl0[2], rl1[2], rl2[2], dist[2];
  #pragma unroll
  for (int e=0;e<2;++e){
    const int ge = ebase + (w<<5) + (e<<4) + (lane&15);
    rn[e] = rowi[ge]; cn[e] = coli[ge];
    const float dx = xbuf[3*rn[e]+0] - xbuf[3*cn[e]+0];
    const float dy = xbuf[3*rn[e]+1] - xbuf[3*cn[e]+1];
    const float dz = xbuf[3*rn[e]+2] - xbuf[3*cn[e]+2];
    rl0[e]=dx; rl1[e]=dy; rl2[e]=dz;
    dist[e] = sqrtf(dx*dx + dy*dy + dz*dz);
  }

  f32x4 acc[2][8];
  #pragma unroll
  for (int s=0;s<8;++s){
    const int f4 = (s<<4)+(q<<2);
    const f32x4 b1 = *(const f32x4*)&bem1v[f4];
    const f32x4 w0 = *(const f32x4*)&wem_rows[f4];
    const f32x4 w1 = *(const f32x4*)&wem_rows[128+f4];
    const f32x4 w2 = *(const f32x4*)&wem_rows[256+f4];
    const f32x4 w3 = *(const f32x4*)&wem_rows[384+f4];
    #pragma unroll
    for (int e=0;e<2;++e)
      #pragma unroll
      for (int r=0;r<4;++r)
        acc[e][s][r] = b1[r] + rl0[e]*w0[r] + rl1[e]*w1[r] + rl2[e]*w2[r] + dist[e]*w3[r];
  }
  const int toff = ((lane&15)<<6) + ((q ^ ((lane>>1)&3))<<4);

  s16x8 B0[2], B1[2];
  #pragma unroll
  for (int e=0;e<2;++e){
    B0[e] = *(const s16x8*)(hb + ((size_t)rn[e]<<7) + q8);
    B1[e] = *(const s16x8*)(hb + ((size_t)rn[e]<<7) + 32 + q8);
  }

  __syncthreads();

  #pragma unroll
  for (int kk=0;kk<8;++kk){
    s16x8 Bn[2];
    if (kk < 6){
      const int k2 = kk+2;
      #pragma unroll
      for (int e=0;e<2;++e){
        const int node = (k2 < 4) ? rn[e] : cn[e];
        Bn[e] = *(const s16x8*)(hb + ((size_t)node<<7) + ((k2&3)<<5) + q8);
      }
    }
    #pragma unroll
    for (int s=0;s<8;++s){
      const s16x8 A = *(const s16x8*)&sm.wbuf[kk][(s<<10)+toff];
      #pragma unroll
      for (int e=0;e<2;++e) acc[e][s] = MFMA(A, B0[e], acc[e][s]);
    }
    #pragma unroll
    for (int e=0;e<2;++e){ B0[e] = B1[e]; if (kk < 6) B1[e] = Bn[e]; }
  }

  s16x8 sb[2][4];
  #pragma unroll
  for (int e=0;e<2;++e)
    #pragma unroll
    for (int c=0;c<4;++c) sb[e][c] = siluPack(acc[e][2*c], acc[e][2*c+1]);

  f32x4 acc2[2][8];
  #pragma unroll
  for (int s=0;s<8;++s){
    const f32x4 b = *(const f32x4*)&bem2v[(s<<4)+(q<<2)];
    #pragma unroll
    for (int e=0;e<2;++e) acc2[e][s] = b;
  }
  #pragma unroll
  for (int c=0;c<4;++c)
    #pragma unroll
    for (int s=0;s<8;++s){
      const s16x8 A = *(const s16x8*)&sm.wbuf[8+c][(s<<10)+toff];
      #pragma unroll
      for (int e=0;e<2;++e) acc2[e][s] = MFMA(A, sb[e][c], acc2[e][s]);
    }

  s16x8 mb[2][4];
  #pragma unroll
  for (int e=0;e<2;++e)
    #pragma unroll
    for (int c=0;c<4;++c) mb[e][c] = siluPack(acc2[e][2*c], acc2[e][2*c+1]);

  f32x4 acc3[2][8];
  #pragma unroll
  for (int s=0;s<8;++s){
    const f32x4 b = *(const f32x4*)&bec1v[(s<<4)+(q<<2)];
    #pragma unroll
    for (int e=0;e<2;++e) acc3[e][s] = b;
  }
  #pragma unroll
  for (int c=0;c<4;++c)
    #pragma unroll
    for (int s=0;s<8;++s){
      const s16x8 A = *(const s16x8*)&sm.wbuf[12+c][(s<<10)+toff];
      #pragma unroll
      for (int e=0;e<2;++e) acc3[e][s] = MFMA(A, mb[e][c], acc3[e][s]);
    }

  float d0[2]={0,0}, d1[2]={0,0}, d2[2]={0,0};
  #pragma unroll
  for (int s=0;s<8;++s){
    const int f4 = (s<<4)+(q<<2);
    const f32x4 w0 = *(const f32x4*)&sm.wcs[0][f4];
    const f32x4 w1 = *(const f32x4*)&sm.wcs[1][f4];
    const f32x4 w2 = *(const f32x4*)&sm.wcs[2][f4];
    #pragma unroll
    for (int e=0;e<2;++e)
      #pragma unroll
      for (int r=0;r<4;++r){
        const float ev = silu_f(acc3[e][s][r]);
        d0[e] += ev*w0[r]; d1[e] += ev*w1[r]; d2[e] += ev*w2[r];
      }
  }
  #pragma unroll
  for (int e=0;e<2;++e){
    d0[e] += __shfl_xor(d0[e],16); d0[e] += __shfl_xor(d0[e],32);
    d1[e] += __shfl_xor(d1[e],16); d1[e] += __shfl_xor(d1[e],32);
    d2[e] += __shfl_xor(d2[e],16); d2[e] += __shfl_xor(d2[e],32);
    if (q < 3){
      const float val = (q==0)?d0[e]:((q==1)?d1[e]:d2[e]);
      atomicAdd(&epsb[(size_t)cn[e]*3 + q], val + bec2[q]);
    }
  }
}

// ---------------- epsilon head: node part ----------------
__global__ __launch_bounds__(256) void k_eps_node(
    const float* __restrict__ hbuf, const float* __restrict__ xbuf,
    const unsigned short* __restrict__ Wh1T, const float* __restrict__ bh1v,
    const float* __restrict__ wh1_rows,
    const float* __restrict__ Wh2, const float* __restrict__ bh2,
    float* __restrict__ epsb)
{
  __shared__ float s_bh1[128], s_w3[3][128], s_wc[3][128];
  const int tid = threadIdx.x;
  if (tid >= 128){
    const int f = tid - 128;
    s_bh1[f]=bh1v[f];
    s_w3[0][f]=wh1_rows[f]; s_w3[1][f]=wh1_rows[128+f]; s_w3[2][f]=wh1_rows[256+f];
    s_wc[0][f]=Wh2[f*3+0]; s_wc[1][f]=Wh2[f*3+1]; s_wc[2][f]=Wh2[f*3+2];
  }
  __syncthreads();
  const int lane = tid & 63, q = lane >> 4;
  const int n = (blockIdx.x<<6) + ((tid>>6)<<4) + (lane & 15);
  const bool valid = n < N_NODES;
  const int nc = valid ? n : (N_NODES-1);
  const float* __restrict__ hp = hbuf + (size_t)nc*HDIM;
  const float x0 = xbuf[3*nc+0], x1 = xbuf[3*nc+1], x2 = xbuf[3*nc+2];
  f32x4 acc[8];
  #pragma unroll
  for (int s=0;s<8;++s)
    #pragma unroll
    for (int r=0;r<4;++r){
      const int f = (s<<4)+(q<<2)+r;
      acc[s][r] = s_bh1[f] + x0*s_w3[0][f] + x1*s_w3[1][f] + x2*s_w3[2][f];
    }
  #pragma unroll
  for (int kk=0;kk<4;++kk){
    const s16x8 bf = ldBf32(hp + (kk<<5), q);
    #pragma unroll
    for (int s=0;s<8;++s) acc[s] = MFMA(ldA(Wh1T, 128, s, kk, lane), bf, acc[s]);
  }
  float d0=0.f, d1=0.f, d2=0.f;
  #pragma unroll
  for (int s=0;s<8;++s)
    #pragma unroll
    for (int r=0;r<4;++r){
      const int f = (s<<4)+(q<<2)+r;
      const float ev = silu_f(acc[s][r]);
      d0 += ev*s_wc[0][f]; d1 += ev*s_wc[1][f]; d2 += ev*s_wc[2][f];
    }
  d0 += __shfl_xor(d0,16); d0 += __shfl_xor(d0,32);
  d1 += __shfl_xor(d1,16); d1 += __shfl_xor(d1,32);
  d2 += __shfl_xor(d2,16); d2 += __shfl_xor(d2,32);
  if (valid && q < 3){
    const float val = (q==0)?d0:((q==1)?d1:d2);
    epsb[(size_t)n*3 + q] += val + bh2[q];
  }
}

extern "C" void kernel_launch(void* const* d_in, const int* in_sizes, int n_in,
                              void* d_out, int out_size, void* d_ws, size_t ws_size,
                              hipStream_t stream)
{
  (void)in_sizes; (void)n_in; (void)out_size;
  const float* h_in  = (const float*)d_in[0];
  const float* x_in  = (const float*)d_in[1];
  const int*   eidx  = (const int*)d_in[2];
  const float* W_emb = (const float*)d_in[3];
  const float* b_emb = (const float*)d_in[4];
  const float* Wm1 = (const float*)d_in[5];
  const float* bm1 = (const float*)d_in[6];
  const float* Wm2 = (const float*)d_in[7];
  const float* bm2 = (const float*)d_in[8];
  const float* Wc1 = (const float*)d_in[9];
  const float* bc1 = (const float*)d_in[10];
  const float* Wc2 = (const float*)d_in[11];
  const float* Wn1 = (const float*)d_in[12];
  const float* bn1 = (const float*)d_in[13];
  const float* Wn2 = (const float*)d_in[14];
  const float* bn2 = (const float*)d_in[15];
  const float* lng = (const float*)d_in[16];
  const float* lnb = (const float*)d_in[17];
  const float* Wem1 = (const float*)d_in[18];
  const float* bem1 = (const float*)d_in[19];
  const float* Wem2 = (const float*)d_in[20];
  const float* bem2 = (const float*)d_in[21];
  const float* Wec1 = (const float*)d_in[22];
  const float* bec1 = (const float*)d_in[23];
  const float* Wec2 = (const float*)d_in[24];
  const float* bec2 = (const float*)d_in[25];
  const float* Wh1 = (const float*)d_in[26];
  const float* bh1 = (const float*)d_in[27];
  const float* Wh2 = (const float*)d_in[28];
  const float* bh2 = (const float*)d_in[29];

  const int* rowi = eidx;
  const int* coli = eidx + N_EDGES;

  float* hbuf = (float*)d_out;
  float* xbuf = hbuf + (size_t)N_NODES*HDIM;
  float* epsb = xbuf + (size_t)N_NODES*3;

  char* wp = (char*)d_ws;
  auto alloc = [&](size_t bytes)->char*{
    char* p = wp; wp += (bytes + 255) & ~(size_t)255; return p;
  };
  unsigned short* WembT = (unsigned short*)alloc((size_t)128*64*2);
  unsigned short *Wn1T[NLAYERS], *Wn2T[NLAYERS];
  for (int i=0;i<NLAYERS;++i){
    Wn1T[i] = (unsigned short*)alloc((size_t)128*256*2);
    Wn2T[i] = (unsigned short*)alloc((size_t)128*128*2);
  }
  unsigned short* Wh1T  = (unsigned short*)alloc((size_t)128*128*2);
  unsigned short* blobL = (unsigned short*)alloc((size_t)NLAYERS*16*4096*2);
  unsigned short* blobE = (unsigned short*)alloc((size_t)16*4096*2);
  unsigned short* hb    = (unsigned short*)alloc((size_t)N_NODES*HDIM*2);
  int* degi   = (int*)alloc((size_t)N_NODES*4);
  int* offv   = (int*)alloc((size_t)N_NODES*4);
  int* cursor = (int*)alloc((size_t)N_NODES*4);
  int* bsum   = (int*)alloc(4096);
  float* cu   = (float*)alloc((size_t)N_NODES*3*4);
  int* perm   = (int*)alloc((size_t)N_EDGES*4);
  char* big   = alloc((size_t)N_EDGES*HDIM*2);       // m_buf (CSR) or agg (atomic)
  const bool use_csr = ((size_t)(wp - (char*)d_ws) <= ws_size);
  unsigned short* m_buf = (unsigned short*)big;
  float* agg = (float*)big;

  // fused weight transposes (1 launch)
  ConvJobs cj;
  cj.j[0] = {W_emb, WembT, 6};
  for (int i=0;i<NLAYERS;++i){
    cj.j[1+i] = {Wn1 + (size_t)i*256*128, Wn1T[i], 8};
    cj.j[4+i] = {Wn2 + (size_t)i*128*128, Wn2T[i], 7};
  }
  cj.j[7] = {Wh1, Wh1T, 7};
  k_conv8<<<dim3(128,8), dim3(256), 0, stream>>>(cj);

  // fused blob builds (1 launch)
  BlobJobs bj;
  for (int i=0;i<NLAYERS;++i)
    bj.j[i] = {Wm1 + (size_t)i*257*128, Wm2 + (size_t)i*128*128,
               Wc1 + (size_t)i*128*128, blobL + (size_t)i*16*4096};
  bj.j[3] = {Wem1, Wem2, Wec1, blobE};
  k_blob4<<<dim3(256,4), dim3(256), 0, stream>>>(bj);

  // fused init (zero degi/cu/epsb + x copy)
  k_init<<<dim3((N_NODES*3+255)/256), dim3(256), 0, stream>>>(x_in, xbuf, cu, epsb, degi);

  k_degree<<<dim3((N_EDGES+255)/256), dim3(256), 0, stream>>>(coli, degi);
  const int nb = (N_NODES + 255)/256;
  if (use_csr){
    k_scanA<<<dim3(nb), dim3(256), 0, stream>>>(degi, offv, bsum);
    k_scanB<<<dim3(1), dim3(256), 0, stream>>>(bsum, nb);
    k_scanC<<<dim3(nb), dim3(256), 0, stream>>>(offv, bsum, cursor);
    k_fill<<<dim3((N_EDGES+255)/256), dim3(256), 0, stream>>>(coli, cursor, perm);
  }
  k_embed<<<dim3((N_NODES+63)/64), dim3(256), 0, stream>>>(h_in, WembT, b_emb, hbuf, hb);

  for (int i=0;i<NLAYERS;++i){
    if (!use_csr) hipMemsetAsync(agg, 0, (size_t)N_NODES*HDIM*4, stream);
    const unsigned short* blob_i = blobL + (size_t)i*16*4096;
    const float* wm1r = Wm1 + (size_t)i*257*128 + (size_t)256*128;
    if (use_csr){
      k_edge_mlp<true><<<dim3(N_EDGES/256), dim3(512), 0, stream>>>(
        hb, xbuf, rowi, coli, perm, blob_i,
        bm1 + i*128, wm1r, bm2 + i*128, bc1 + i*128, Wc2 + i*128,
        m_buf, agg, cu);
      k_node_mlp<true><<<dim3((N_NODES+63)/64), dim3(256), 0, stream>>>(
        hbuf, hb, xbuf, m_buf, agg, offv, degi, cu,
        Wn1T[i], bn1 + i*128, Wn2T[i], bn2 + i*128, lng + i*128, lnb + i*128);
    } else {
      k_edge_mlp<false><<<dim3(N_EDGES/256), dim3(512), 0, stream>>>(
        hb, xbuf, rowi, coli, perm, blob_i,
        bm1 + i*128, wm1r, bm2 + i*128, bc1 + i*128, Wc2 + i*128,
        m_buf, agg, cu);
      k_node_mlp<false><<<dim3((N_NODES+63)/64), dim3(256), 0, stream>>>(
        hbuf, hb, xbuf, m_buf, agg, offv, degi, cu,
        Wn1T[i], bn1 + i*128, Wn2T[i], bn2 + i*128, lng + i*128, lnb + i*128);
    }
  }
  k_eps_edge<<<dim3(N_EDGES/256), dim3(512), 0, stream>>>(
    hb, xbuf, rowi, coli, blobE,
    bem1, Wem1 + (size_t)256*128, bem2, bec1, Wec2, bec2, epsb);
  k_eps_node<<<dim3((N_NODES+63)/64), dim3(256), 0, stream>>>(
    hbuf, xbuf, Wh1T, bh1, Wh1 + (size_t)128*128, Wh2, bh2, epsb);
}

// Round 8
// 1373.197 us; speedup vs baseline: 1.0476x; 1.0476x over previous
//
#include <hip/hip_runtime.h>

#define N_NODES 50000
#define N_EDGES 640000
#define HDIM    128
#define NLAYERS 3

typedef __attribute__((ext_vector_type(4))) float f32x4;
typedef short s16x8 __attribute__((ext_vector_type(8)));
typedef __bf16 bf16v8 __attribute__((ext_vector_type(8)));

static __device__ __forceinline__ unsigned short f2b(float f){
  unsigned int u = __float_as_uint(f);
  unsigned int r = u + 0x7FFFu + ((u >> 16) & 1u);
  return (unsigned short)(r >> 16);
}
static __device__ __forceinline__ float b2f(unsigned short h){
  return __uint_as_float(((unsigned int)h) << 16);
}
static __device__ __forceinline__ float silu_f(float x){
  return x / (1.0f + __expf(-x));
}
static __device__ __forceinline__ unsigned int cvt2(float a, float b){
  unsigned int r;
  asm("v_cvt_pk_bf16_f32 %0, %1, %2" : "=v"(r) : "v"(a), "v"(b));
  return r;
}
static __device__ __forceinline__ s16x8 siluPack(const f32x4 a, const f32x4 b){
  union { unsigned int u[4]; s16x8 v; } r;
  r.u[0] = cvt2(silu_f(a[0]), silu_f(a[1]));
  r.u[1] = cvt2(silu_f(a[2]), silu_f(a[3]));
  r.u[2] = cvt2(silu_f(b[0]), silu_f(b[1]));
  r.u[3] = cvt2(silu_f(b[2]), silu_f(b[3]));
  return r.v;
}
static __device__ __forceinline__ f32x4 MFMA(s16x8 a, s16x8 b, f32x4 c){
  return __builtin_amdgcn_mfma_f32_16x16x32_bf16(
      __builtin_bit_cast(bf16v8, a), __builtin_bit_cast(bf16v8, b), c, 0, 0, 0);
}

// A-fragment from global (node/embed kernels): WT[out][K] row-major
static __device__ __forceinline__ s16x8 ldA(const unsigned short* __restrict__ WT,
                                            int K, int s, int kk, int lane){
  const unsigned short* p = WT + (size_t)((s<<4) + (lane&15))*K + (kk<<5) + ((lane>>4)<<2);
  ushort4 a = *(const ushort4*)p;
  ushort4 b = *(const ushort4*)(p + 16);
  s16x8 r;
  r[0]=(short)a.x; r[1]=(short)a.y; r[2]=(short)a.z; r[3]=(short)a.w;
  r[4]=(short)b.x; r[5]=(short)b.y; r[6]=(short)b.z; r[7]=(short)b.w;
  return r;
}
static __device__ __forceinline__ s16x8 ldBf32(const float* __restrict__ p, int q){
  float4 a = *(const float4*)(p + (q<<2));
  float4 b = *(const float4*)(p + 16 + (q<<2));
  s16x8 r;
  r[0]=(short)f2b(a.x); r[1]=(short)f2b(a.y); r[2]=(short)f2b(a.z); r[3]=(short)f2b(a.w);
  r[4]=(short)f2b(b.x); r[5]=(short)f2b(b.y); r[6]=(short)f2b(b.z); r[7]=(short)f2b(b.w);
  return r;
}

#define GLL(SRC, DST) __builtin_amdgcn_global_load_lds( \
    (const __attribute__((address_space(1))) void*)(SRC), \
    (__attribute__((address_space(3))) void*)(DST), 16, 0, 0)

// segmented-run atomic add: lanes within a 16-lane group hold consecutive
// CSR slots; reduce runs of equal `key` then one atomic per run.
static __device__ __forceinline__ void segAtomicAdd(float* addr_base, int key,
                                                    float v, int lane, int q){
  #pragma unroll
  for (int d=1; d<16; d<<=1){
    const float ov = __shfl_up(v, d);
    const int  ok = __shfl_up(key, d);
    if ((lane&15) >= d && ok == key) v += ov;
  }
  const int nk = __shfl_down(key, 1);
  const bool last = ((lane&15)==15) || (nk != key);
  if (last) atomicAdd(addr_base + (size_t)key*3 + q, v);
}

// ---------------- fused weight transposes (8 jobs, 1 launch) ----------------
struct ConvJob { const float* src; unsigned short* dst; int kshift; };
struct ConvJobs { ConvJob j[8]; };
__global__ void k_conv8(ConvJobs jobs){
  const ConvJob jb = jobs.j[blockIdx.y];
  const int K = 1 << jb.kshift;
  const int idx = (blockIdx.x<<8) + threadIdx.x;
  if (idx < (K<<7)){
    const int n = idx >> jb.kshift;
    const int k = idx & (K-1);
    jb.dst[idx] = f2b(jb.src[(size_t)k*HDIM + n]);
  }
}

// blob: 16 tiles of 4096 bf16. t=0..7: W1 (K=256); 8..11: W2; 12..15: W3.
struct BlobJob { const float *W1, *W2, *W3; unsigned short* dst; };
struct BlobJobs { BlobJob j[4]; };
__global__ void k_blob4(BlobJobs jobs){
  const BlobJob jb = jobs.j[blockIdx.y];
  const int i = (blockIdx.x<<8) + threadIdx.x;   // < 65536
  const int t = i >> 12;
  const int n = (i >> 5) & 127;
  const int slot = (i >> 3) & 3;
  const int j = i & 7;
  const int q = slot ^ ((n >> 1) & 3);
  const int kl = ((j >> 2) << 4) + (q << 2) + (j & 3);
  float v;
  if (t < 8)       v = jb.W1[(size_t)((t<<5)+kl)*HDIM + n];
  else if (t < 12) v = jb.W2[(size_t)(((t-8)<<5)+kl)*HDIM + n];
  else             v = jb.W3[(size_t)(((t-12)<<5)+kl)*HDIM + n];
  jb.dst[i] = f2b(v);
}

// ---------------- fused init: zero degi/cu/epsb + copy x ----------------
__global__ void k_init(const float* __restrict__ xin, float* __restrict__ xbuf,
                       float* __restrict__ cu, float* __restrict__ epsb,
                       int* __restrict__ degi){
  const int i = (blockIdx.x<<8) + threadIdx.x;
  if (i < N_NODES*3){ xbuf[i] = xin[i]; cu[i] = 0.f; epsb[i] = 0.f; }
  if (i < N_NODES) degi[i] = 0;
}

// ---------------- CSR build ----------------
__global__ void k_degree(const int* __restrict__ coli, int* __restrict__ degi){
  const int e = (blockIdx.x<<8) + threadIdx.x;
  if (e < N_EDGES) atomicAdd(&degi[coli[e]], 1);
}
__global__ void k_scanA(const int* __restrict__ degi, int* __restrict__ off, int* __restrict__ bsum){
  const int t = threadIdx.x, b = blockIdx.x;
  const int i = (b<<8) + t;
  const int v = (i < N_NODES) ? degi[i] : 0;
  int x = v;
  const int lane = t & 63;
  #pragma unroll
  for (int d=1; d<64; d<<=1){ int y = __shfl_up(x, d); if (lane >= d) x += y; }
  __shared__ int wsum[4];
  if (lane == 63) wsum[t>>6] = x;
  __syncthreads();
  int wo = 0;
  #pragma unroll
  for (int w=0; w<4; ++w) if (w < (t>>6)) wo += wsum[w];
  const int incl = x + wo;
  if (i < N_NODES) off[i] = incl - v;
  if (t == 255) bsum[b] = incl;
}
__global__ void k_scanB(int* __restrict__ bsum, int nb){
  const int t = threadIdx.x;
  const int v = (t < nb) ? bsum[t] : 0;
  int x = v;
  const int lane = t & 63;
  #pragma unroll
  for (int d=1; d<64; d<<=1){ int y = __shfl_up(x, d); if (lane >= d) x += y; }
  __shared__ int wsum[4];
  if (lane == 63) wsum[t>>6] = x;
  __syncthreads();
  int wo = 0;
  #pragma unroll
  for (int w=0; w<4; ++w) if (w < (t>>6)) wo += wsum[w];
  const int incl = x + wo;
  if (t < nb) bsum[t] = incl - v;
}
__global__ void k_scanC(int* __restrict__ off, const int* __restrict__ bsum, int* __restrict__ cursor){
  const int i = (blockIdx.x<<8) + threadIdx.x;
  if (i < N_NODES){
    const int o = off[i] + bsum[i>>8];
    off[i] = o;
    cursor[i] = o;
  }
}
// fill sorted edge arrays: slot p (CSR order by col) -> row/col
__global__ void k_fill(const int* __restrict__ rowi, const int* __restrict__ coli,
                       int* __restrict__ cursor,
                       int* __restrict__ rowS, int* __restrict__ colS){
  const int e = (blockIdx.x<<8) + threadIdx.x;
  if (e < N_EDGES){
    const int c = coli[e];
    const int p = atomicAdd(&cursor[c], 1);
    rowS[p] = rowi[e];
    colS[p] = c;
  }
}

// ---------------- embedding: h = h_in @ W_emb + b_emb (+ bf16 mirror) --------
__global__ __launch_bounds__(256) void k_embed(
    const float* __restrict__ hin, const unsigned short* __restrict__ WembT,
    const float* __restrict__ bemb, float* __restrict__ hbuf,
    unsigned short* __restrict__ hb)
{
  __shared__ float s_b[128];
  const int tid = threadIdx.x;
  if (tid < 128) s_b[tid] = bemb[tid];
  __syncthreads();
  const int lane = tid & 63, q = lane>>4;
  const int n = (blockIdx.x<<6) + ((tid>>6)<<4) + (lane&15);
  const bool valid = n < N_NODES;
  const int nc = valid ? n : (N_NODES-1);
  const float* __restrict__ hp = hin + (size_t)nc*64;
  f32x4 acc[8];
  #pragma unroll
  for (int s=0;s<8;++s)
    #pragma unroll
    for (int r=0;r<4;++r) acc[s][r] = s_b[(s<<4)+(q<<2)+r];
  #pragma unroll
  for (int kk=0;kk<2;++kk){
    const s16x8 bf = ldBf32(hp + (kk<<5), q);
    #pragma unroll
    for (int s=0;s<8;++s) acc[s] = MFMA(ldA(WembT, 64, s, kk, lane), bf, acc[s]);
  }
  if (valid){
    float* op = hbuf + (size_t)n*HDIM;
    unsigned short* hbw = hb + (size_t)n*HDIM;
    #pragma unroll
    for (int s=0;s<8;++s){
      float4 o; o.x=acc[s][0]; o.y=acc[s][1]; o.z=acc[s][2]; o.w=acc[s][3];
      *(float4*)(op + (s<<4) + (q<<2)) = o;
      ushort4 u; u.x=f2b(o.x); u.y=f2b(o.y); u.z=f2b(o.z); u.w=f2b(o.w);
      *(ushort4*)(hbw + ((s>>1)<<5) + (q<<3) + ((s&1)<<2)) = u;
    }
  }
}

// ------- per-layer edge MLP: CSR-sorted edges, whole-blob LDS-resident ------
// 1024 threads (16 waves, 4/SIMD), 2 edges/thread, 512 edges/block, 1250 blocks.
__global__ __launch_bounds__(1024,1) void k_edge_mlp(
    const unsigned short* __restrict__ hb, const float* __restrict__ xbuf,
    const int* __restrict__ rowS, const int* __restrict__ colS,
    const unsigned short* __restrict__ blob,
    const float* __restrict__ bm1v, const float* __restrict__ wm1r,
    const float* __restrict__ bm2v, const float* __restrict__ bc1v,
    const float* __restrict__ wc2v,
    unsigned short* __restrict__ m_buf, float* __restrict__ cu)
{
  __shared__ struct {
    __align__(16) unsigned char wbuf[16][8192];   // 128 KiB weights
    float rdS[3][512];
  } sm;
  const int tid = threadIdx.x, lane = tid & 63, q = lane >> 4;
  const int w = tid >> 6;
  const int q8 = q << 3;
  const int ebase = blockIdx.x << 9;

  // stage entire blob once (8 x 16B per thread, linear)
  {
    const unsigned short* bsrc = blob + (tid<<3);
    unsigned char* bdst = ((unsigned char*)sm.wbuf) + (tid<<4);
    #pragma unroll
    for (int i=0;i<8;++i)
      GLL(bsrc + (i<<13), bdst + (i<<14));
  }

  int rn[2], cn[2];
  float dist[2];
  #pragma unroll
  for (int e=0;e<2;++e){
    const int el = (w<<5) + (e<<4) + (lane&15);
    const int ge = ebase + el;
    rn[e] = rowS[ge]; cn[e] = colS[ge];
    const float dx = xbuf[3*rn[e]+0] - xbuf[3*cn[e]+0];
    const float dy = xbuf[3*rn[e]+1] - xbuf[3*cn[e]+1];
    const float dz = xbuf[3*rn[e]+2] - xbuf[3*cn[e]+2];
    const float d = sqrtf(dx*dx + dy*dy + dz*dz);
    dist[e] = d;
    if (q == 0){
      const float inv = 1.0f / (d + 1e-8f);
      sm.rdS[0][el] = dx*inv; sm.rdS[1][el] = dy*inv; sm.rdS[2][el] = dz*inv;
    }
  }

  f32x4 acc[2][8];
  #pragma unroll
  for (int s=0;s<8;++s){
    const f32x4 b1 = *(const f32x4*)&bm1v[(s<<4)+(q<<2)];
    const f32x4 wv = *(const f32x4*)&wm1r[(s<<4)+(q<<2)];
    #pragma unroll
    for (int e=0;e<2;++e)
      #pragma unroll
      for (int r=0;r<4;++r) acc[e][s][r] = b1[r] + dist[e]*wv[r];
  }
  const int toff = ((lane&15)<<6) + ((q ^ ((lane>>1)&3))<<4);

  // depth-2 B prefetch pipeline
  s16x8 B0[2], B1[2];
  #pragma unroll
  for (int e=0;e<2;++e){
    B0[e] = *(const s16x8*)(hb + ((size_t)rn[e]<<7) + q8);
    B1[e] = *(const s16x8*)(hb + ((size_t)rn[e]<<7) + 32 + q8);
  }

  __syncthreads();   // drains staging + metadata; only barrier

  #pragma unroll
  for (int kk=0;kk<8;++kk){
    s16x8 Bn[2];
    if (kk < 6){
      const int k2 = kk+2;
      #pragma unroll
      for (int e=0;e<2;++e){
        const int node = (k2 < 4) ? rn[e] : cn[e];
        Bn[e] = *(const s16x8*)(hb + ((size_t)node<<7) + ((k2&3)<<5) + q8);
      }
    }
    #pragma unroll
    for (int s=0;s<8;++s){
      const s16x8 A = *(const s16x8*)&sm.wbuf[kk][(s<<10)+toff];
      #pragma unroll
      for (int e=0;e<2;++e) acc[e][s] = MFMA(A, B0[e], acc[e][s]);
    }
    #pragma unroll
    for (int e=0;e<2;++e){ B0[e] = B1[e]; if (kk < 6) B1[e] = Bn[e]; }
  }

  s16x8 sb[2][4];
  #pragma unroll
  for (int e=0;e<2;++e)
    #pragma unroll
    for (int c=0;c<4;++c) sb[e][c] = siluPack(acc[e][2*c], acc[e][2*c+1]);

  f32x4 acc2[2][8];
  #pragma unroll
  for (int s=0;s<8;++s){
    const f32x4 b = *(const f32x4*)&bm2v[(s<<4)+(q<<2)];
    #pragma unroll
    for (int e=0;e<2;++e) acc2[e][s] = b;
  }
  #pragma unroll
  for (int c=0;c<4;++c)
    #pragma unroll
    for (int s=0;s<8;++s){
      const s16x8 A = *(const s16x8*)&sm.wbuf[8+c][(s<<10)+toff];
      #pragma unroll
      for (int e=0;e<2;++e) acc2[e][s] = MFMA(A, sb[e][c], acc2[e][s]);
    }

  s16x8 mb[2][4];
  #pragma unroll
  for (int e=0;e<2;++e)
    #pragma unroll
    for (int c=0;c<4;++c) mb[e][c] = siluPack(acc2[e][2*c], acc2[e][2*c+1]);

  f32x4 acc3[2][8];
  #pragma unroll
  for (int s=0;s<8;++s){
    const f32x4 b = *(const f32x4*)&bc1v[(s<<4)+(q<<2)];
    #pragma unroll
    for (int e=0;e<2;++e) acc3[e][s] = b;
  }
  #pragma unroll
  for (int c=0;c<4;++c)
    #pragma unroll
    for (int s=0;s<8;++s){
      const s16x8 A = *(const s16x8*)&sm.wbuf[12+c][(s<<10)+toff];
      #pragma unroll
      for (int e=0;e<2;++e) acc3[e][s] = MFMA(A, mb[e][c], acc3[e][s]);
    }

  // epilogue: coord scatter (segmented atomics, cols sorted) + sequential m store
  float dot[2] = {0.f,0.f};
  #pragma unroll
  for (int s=0;s<8;++s){
    const f32x4 wv = *(const f32x4*)&wc2v[(s<<4)+(q<<2)];
    #pragma unroll
    for (int e=0;e<2;++e)
      #pragma unroll
      for (int r=0;r<4;++r) dot[e] += silu_f(acc3[e][s][r]) * wv[r];
  }
  #pragma unroll
  for (int e=0;e<2;++e){
    dot[e] += __shfl_xor(dot[e], 16);
    dot[e] += __shfl_xor(dot[e], 32);
    const float cm = tanhf(dot[e]);
    const int el = (w<<5) + (e<<4) + (lane&15);
    if (q < 3)
      segAtomicAdd(cu, cn[e], cm * sm.rdS[q][el], lane, q);
  }
  #pragma unroll
  for (int e=0;e<2;++e){
    const int ge = ebase + (w<<5) + (e<<4) + (lane&15);
    unsigned short* mp = m_buf + ((size_t)ge<<7) + q8;
    #pragma unroll
    for (int c=0;c<4;++c) *(s16x8*)(mp + (c<<5)) = mb[e][c];
  }
}

// ---------------- per-layer node update (sequential m_buf; zeroes cu) --------
__global__ __launch_bounds__(256) void k_node_mlp(
    float* __restrict__ hbuf, unsigned short* __restrict__ hb,
    float* __restrict__ xbuf,
    const unsigned short* __restrict__ m_buf,
    const int* __restrict__ off, const int* __restrict__ degi,
    float* __restrict__ cu,
    const unsigned short* __restrict__ Wn1T, const float* __restrict__ bn1v,
    const unsigned short* __restrict__ Wn2T, const float* __restrict__ bn2v,
    const float* __restrict__ lng, const float* __restrict__ lnb)
{
  __shared__ float s_bn1[128], s_bn2[128], s_g[128], s_b[128];
  const int tid = threadIdx.x;
  const int nbase = blockIdx.x << 6;
  if (tid >= 128){
    const int f = tid - 128;
    s_bn1[f]=bn1v[f]; s_bn2[f]=bn2v[f]; s_g[f]=lng[f]; s_b[f]=lnb[f];
  } else if (tid < 64){
    const int n = nbase + tid;
    if (n < N_NODES){
      const float dd = (float)degi[n] + 1.0f;
      #pragma unroll
      for (int c=0;c<3;++c){
        xbuf[3*n+c] += cu[3*n+c] / dd;
        cu[3*n+c] = 0.f;
      }
    }
  }
  __syncthreads();

  const int lane = tid & 63, q = lane >> 4;
  const int q8 = q << 3;
  const int n = nbase + ((tid>>6)<<4) + (lane & 15);
  const bool valid = (n < N_NODES);
  const int nc = valid ? n : (N_NODES-1);
  const float* __restrict__ hp = hbuf + (size_t)nc*HDIM;
  const unsigned short* __restrict__ hbp = hb + (size_t)nc*HDIM;

  float aggv[4][8];
  #pragma unroll
  for (int kk=0;kk<4;++kk)
    #pragma unroll
    for (int j=0;j<8;++j) aggv[kk][j]=0.f;
  {
    const int st = off[nc];
    const int cnt = degi[nc];
    for (int ii=0; ii<cnt; ++ii){
      const unsigned short* mrow = m_buf + ((size_t)(st+ii)<<7);
      #pragma unroll
      for (int kk=0;kk<4;++kk){
        const s16x8 v = *(const s16x8*)(mrow + (kk<<5) + q8);
        #pragma unroll
        for (int j=0;j<8;++j) aggv[kk][j] += b2f((unsigned short)v[j]);
      }
    }
  }

  f32x4 acc[8];
  #pragma unroll
  for (int s=0;s<8;++s)
    #pragma unroll
    for (int r=0;r<4;++r) acc[s][r] = s_bn1[(s<<4)+(q<<2)+r];
  #pragma unroll
  for (int kk=0;kk<4;++kk){
    const s16x8 bf = *(const s16x8*)(hbp + (kk<<5) + q8);
    #pragma unroll
    for (int s=0;s<8;++s) acc[s] = MFMA(ldA(Wn1T, 256, s, kk, lane), bf, acc[s]);
  }
  #pragma unroll
  for (int kk=0;kk<4;++kk){
    s16x8 bf;
    #pragma unroll
    for (int j=0;j<8;++j) bf[j] = (short)f2b(aggv[kk][j]);
    #pragma unroll
    for (int s=0;s<8;++s) acc[s] = MFMA(ldA(Wn1T, 256, s, kk+4, lane), bf, acc[s]);
  }
  s16x8 sb[4];
  #pragma unroll
  for (int t=0;t<4;++t)
    #pragma unroll
    for (int j=0;j<8;++j)
      sb[t][j] = (short)f2b(silu_f(acc[(t<<1)+(j>>2)][j&3]));
  f32x4 acc2[8];
  #pragma unroll
  for (int s=0;s<8;++s)
    #pragma unroll
    for (int r=0;r<4;++r) acc2[s][r] = s_bn2[(s<<4)+(q<<2)+r];
  #pragma unroll
  for (int kk=0;kk<4;++kk){
    #pragma unroll
    for (int s=0;s<8;++s) acc2[s] = MFMA(ldA(Wn2T, 128, s, kk, lane), sb[kk], acc2[s]);
  }

  float v[8][4];
  float sum = 0.f;
  #pragma unroll
  for (int s=0;s<8;++s){
    float4 h4 = *(const float4*)(hp + (s<<4) + (q<<2));
    v[s][0] = h4.x + acc2[s][0]; v[s][1] = h4.y + acc2[s][1];
    v[s][2] = h4.z + acc2[s][2]; v[s][3] = h4.w + acc2[s][3];
    sum += v[s][0]+v[s][1]+v[s][2]+v[s][3];
  }
  sum += __shfl_xor(sum, 16);
  sum += __shfl_xor(sum, 32);
  const float mu = sum * (1.0f/128.0f);
  float vs = 0.f;
  #pragma unroll
  for (int s=0;s<8;++s)
    #pragma unroll
    for (int r=0;r<4;++r){ const float d = v[s][r]-mu; vs += d*d; }
  vs += __shfl_xor(vs, 16);
  vs += __shfl_xor(vs, 32);
  const float rs = rsqrtf(vs*(1.0f/128.0f) + 1e-5f);
  if (valid){
    float* op = hbuf + (size_t)n*HDIM;
    unsigned short* hbw = hb + (size_t)n*HDIM;
    #pragma unroll
    for (int s=0;s<8;++s){
      const int f0 = (s<<4)+(q<<2);
      float4 o;
      o.x = (v[s][0]-mu)*rs*s_g[f0+0] + s_b[f0+0];
      o.y = (v[s][1]-mu)*rs*s_g[f0+1] + s_b[f0+1];
      o.z = (v[s][2]-mu)*rs*s_g[f0+2] + s_b[f0+2];
      o.w = (v[s][3]-mu)*rs*s_g[f0+3] + s_b[f0+3];
      *(float4*)(op + f0) = o;
      ushort4 u; u.x=f2b(o.x); u.y=f2b(o.y); u.z=f2b(o.z); u.w=f2b(o.w);
      *(ushort4*)(hbw + ((s>>1)<<5) + q8 + ((s&1)<<2)) = u;
    }
  }
}

// ---------------- epsilon head: edge part (CSR-sorted) ----------------
__global__ __launch_bounds__(1024,1) void k_eps_edge(
    const unsigned short* __restrict__ hb, const float* __restrict__ xbuf,
    const int* __restrict__ rowS, const int* __restrict__ colS,
    const unsigned short* __restrict__ blob,
    const float* __restrict__ bem1v, const float* __restrict__ wem_rows,
    const float* __restrict__ bem2v, const float* __restrict__ bec1v,
    const float* __restrict__ Wec2, const float* __restrict__ bec2,
    float* __restrict__ epsb)
{
  __shared__ struct {
    __align__(16) unsigned char wbuf[16][8192];
    float wcs[3][128];
  } sm;
  const int tid = threadIdx.x, lane = tid & 63, q = lane >> 4;
  const int w = tid >> 6;
  const int q8 = q << 3;
  const int ebase = blockIdx.x << 9;

  {
    const unsigned short* bsrc = blob + (tid<<3);
    unsigned char* bdst = ((unsigned char*)sm.wbuf) + (tid<<4);
    #pragma unroll
    for (int i=0;i<8;++i)
      GLL(bsrc + (i<<13), bdst + (i<<14));
  }
  if (tid < 128){
    sm.wcs[0][tid] = Wec2[tid*3+0];
    sm.wcs[1][tid] = Wec2[tid*3+1];
    sm.wcs[2][tid] = Wec2[tid*3+2];
  }

  int rn[2], cn[2];
  float rl0[2], rl1[2], rl2[2], dist[2];
  #pragma unroll
  for (int e=0;e<2;++e){
    const int ge = ebase + (w<<5) + (e<<4) + (lane&15);
    rn[e] = rowS[ge]; cn[e] = colS[ge];
    const float dx = xbuf[3*rn[e]+0] - xbuf[3*cn[e]+0];
    const float dy = xbuf[3*rn[e]+1] - xbuf[3*cn[e]+1];
    const float dz = xbuf[3*rn[e]+2] - xbuf[3*cn[e]+2];
    rl0[e]=dx; rl1[e]=dy; rl2[e]=dz;
    dist[e] = sqrtf(dx*dx + dy*dy + dz*dz);
  }

  f32x4 acc[2][8];
  #pragma unroll
  for (int s=0;s<8;++s){
    const int f4 = (s<<4)+(q<<2);
    const f32x4 b1 = *(const f32x4*)&bem1v[f4];
    const f32x4 w0 = *(const f32x4*)&wem_rows[f4];
    const f32x4 w1 = *(const f32x4*)&wem_rows[128+f4];
    const f32x4 w2 = *(const f32x4*)&wem_rows[256+f4];
    const f32x4 w3 = *(const f32x4*)&wem_rows[384+f4];
    #pragma unroll
    for (int e=0;e<2;++e)
      #pragma unroll
      for (int r=0;r<4;++r)
        acc[e][s][r] = b1[r] + rl0[e]*w0[r] + rl1[e]*w1[r] + rl2[e]*w2[r] + dist[e]*w3[r];
  }
  const int toff = ((lane&15)<<6) + ((q ^ ((lane>>1)&3))<<4);

  s16x8 B0[2], B1[2];
  #pragma unroll
  for (int e=0;e<2;++e){
    B0[e] = *(const s16x8*)(hb + ((size_t)rn[e]<<7) + q8);
    B1[e] = *(const s16x8*)(hb + ((size_t)rn[e]<<7) + 32 + q8);
  }

  __syncthreads();

  #pragma unroll
  for (int kk=0;kk<8;++kk){
    s16x8 Bn[2];
    if (kk < 6){
      const int k2 = kk+2;
      #pragma unroll
      for (int e=0;e<2;++e){
        const int node = (k2 < 4) ? rn[e] : cn[e];
        Bn[e] = *(const s16x8*)(hb + ((size_t)node<<7) + ((k2&3)<<5) + q8);
      }
    }
    #pragma unroll
    for (int s=0;s<8;++s){
      const s16x8 A = *(const s16x8*)&sm.wbuf[kk][(s<<10)+toff];
      #pragma unroll
      for (int e=0;e<2;++e) acc[e][s] = MFMA(A, B0[e], acc[e][s]);
    }
    #pragma unroll
    for (int e=0;e<2;++e){ B0[e] = B1[e]; if (kk < 6) B1[e] = Bn[e]; }
  }

  s16x8 sb[2][4];
  #pragma unroll
  for (int e=0;e<2;++e)
    #pragma unroll
    for (int c=0;c<4;++c) sb[e][c] = siluPack(acc[e][2*c], acc[e][2*c+1]);

  f32x4 acc2[2][8];
  #pragma unroll
  for (int s=0;s<8;++s){
    const f32x4 b = *(const f32x4*)&bem2v[(s<<4)+(q<<2)];
    #pragma unroll
    for (int e=0;e<2;++e) acc2[e][s] = b;
  }
  #pragma unroll
  for (int c=0;c<4;++c)
    #pragma unroll
    for (int s=0;s<8;++s){
      const s16x8 A = *(const s16x8*)&sm.wbuf[8+c][(s<<10)+toff];
      #pragma unroll
      for (int e=0;e<2;++e) acc2[e][s] = MFMA(A, sb[e][c], acc2[e][s]);
    }

  s16x8 mb[2][4];
  #pragma unroll
  for (int e=0;e<2;++e)
    #pragma unroll
    for (int c=0;c<4;++c) mb[e][c] = siluPack(acc2[e][2*c], acc2[e][2*c+1]);

  f32x4 acc3[2][8];
  #pragma unroll
  for (int s=0;s<8;++s){
    const f32x4 b = *(const f32x4*)&bec1v[(s<<4)+(q<<2)];
    #pragma unroll
    for (int e=0;e<2;++e) acc3[e][s] = b;
  }
  #pragma unroll
  for (int c=0;c<4;++c)
    #pragma unroll
    for (int s=0;s<8;++s){
      const s16x8 A = *(const s16x8*)&sm.wbuf[12+c][(s<<10)+toff];
      #pragma unroll
      for (int e=0;e<2;++e) acc3[e][s] = MFMA(A, mb[e][c], acc3[e][s]);
    }

  float d0[2]={0,0}, d1[2]={0,0}, d2[2]={0,0};
  #pragma unroll
  for (int s=0;s<8;++s){
    const int f4 = (s<<4)+(q<<2);
    const f32x4 w0 = *(const f32x4*)&sm.wcs[0][f4];
    const f32x4 w1 = *(const f32x4*)&sm.wcs[1][f4];
    const f32x4 w2 = *(const f32x4*)&sm.wcs[2][f4];
    #pragma unroll
    for (int e=0;e<2;++e)
      #pragma unroll
      for (int r=0;r<4;++r){
        const float ev = silu_f(acc3[e][s][r]);
        d0[e] += ev*w0[r]; d1[e] += ev*w1[r]; d2[e] += ev*w2[r];
      }
  }
  #pragma unroll
  for (int e=0;e<2;++e){
    d0[e] += __shfl_xor(d0[e],16); d0[e] += __shfl_xor(d0[e],32);
    d1[e] += __shfl_xor(d1[e],16); d1[e] += __shfl_xor(d1[e],32);
    d2[e] += __shfl_xor(d2[e],16); d2[e] += __shfl_xor(d2[e],32);
    if (q < 3){
      const float val = ((q==0)?d0[e]:((q==1)?d1[e]:d2[e])) + bec2[q];
      segAtomicAdd(epsb, cn[e], val, lane, q);
    }
  }
}

// ---------------- epsilon head: node part ----------------
__global__ __launch_bounds__(256) void k_eps_node(
    const float* __restrict__ hbuf, const float* __restrict__ xbuf,
    const unsigned short* __restrict__ Wh1T, const float* __restrict__ bh1v,
    const float* __restrict__ wh1_rows,
    const float* __restrict__ Wh2, const float* __restrict__ bh2,
    float* __restrict__ epsb)
{
  __shared__ float s_bh1[128], s_w3[3][128], s_wc[3][128];
  const int tid = threadIdx.x;
  if (tid >= 128){
    const int f = tid - 128;
    s_bh1[f]=bh1v[f];
    s_w3[0][f]=wh1_rows[f]; s_w3[1][f]=wh1_rows[128+f]; s_w3[2][f]=wh1_rows[256+f];
    s_wc[0][f]=Wh2[f*3+0]; s_wc[1][f]=Wh2[f*3+1]; s_wc[2][f]=Wh2[f*3+2];
  }
  __syncthreads();
  const int lane = tid & 63, q = lane >> 4;
  const int n = (blockIdx.x<<6) + ((tid>>6)<<4) + (lane & 15);
  const bool valid = n < N_NODES;
  const int nc = valid ? n : (N_NODES-1);
  const float* __restrict__ hp = hbuf + (size_t)nc*HDIM;
  const float x0 = xbuf[3*nc+0], x1 = xbuf[3*nc+1], x2 = xbuf[3*nc+2];
  f32x4 acc[8];
  #pragma unroll
  for (int s=0;s<8;++s)
    #pragma unroll
    for (int r=0;r<4;++r){
      const int f = (s<<4)+(q<<2)+r;
      acc[s][r] = s_bh1[f] + x0*s_w3[0][f] + x1*s_w3[1][f] + x2*s_w3[2][f];
    }
  #pragma unroll
  for (int kk=0;kk<4;++kk){
    const s16x8 bf = ldBf32(hp + (kk<<5), q);
    #pragma unroll
    for (int s=0;s<8;++s) acc[s] = MFMA(ldA(Wh1T, 128, s, kk, lane), bf, acc[s]);
  }
  float d0=0.f, d1=0.f, d2=0.f;
  #pragma unroll
  for (int s=0;s<8;++s)
    #pragma unroll
    for (int r=0;r<4;++r){
      const int f = (s<<4)+(q<<2)+r;
      const float ev = silu_f(acc[s][r]);
      d0 += ev*s_wc[0][f]; d1 += ev*s_wc[1][f]; d2 += ev*s_wc[2][f];
    }
  d0 += __shfl_xor(d0,16); d0 += __shfl_xor(d0,32);
  d1 += __shfl_xor(d1,16); d1 += __shfl_xor(d1,32);
  d2 += __shfl_xor(d2,16); d2 += __shfl_xor(d2,32);
  if (valid && q < 3){
    const float val = (q==0)?d0:((q==1)?d1:d2);
    epsb[(size_t)n*3 + q] += val + bh2[q];
  }
}

extern "C" void kernel_launch(void* const* d_in, const int* in_sizes, int n_in,
                              void* d_out, int out_size, void* d_ws, size_t ws_size,
                              hipStream_t stream)
{
  (void)in_sizes; (void)n_in; (void)out_size; (void)ws_size;
  const float* h_in  = (const float*)d_in[0];
  const float* x_in  = (const float*)d_in[1];
  const int*   eidx  = (const int*)d_in[2];
  const float* W_emb = (const float*)d_in[3];
  const float* b_emb = (const float*)d_in[4];
  const float* Wm1 = (const float*)d_in[5];
  const float* bm1 = (const float*)d_in[6];
  const float* Wm2 = (const float*)d_in[7];
  const float* bm2 = (const float*)d_in[8];
  const float* Wc1 = (const float*)d_in[9];
  const float* bc1 = (const float*)d_in[10];
  const float* Wc2 = (const float*)d_in[11];
  const float* Wn1 = (const float*)d_in[12];
  const float* bn1 = (const float*)d_in[13];
  const float* Wn2 = (const float*)d_in[14];
  const float* bn2 = (const float*)d_in[15];
  const float* lng = (const float*)d_in[16];
  const float* lnb = (const float*)d_in[17];
  const float* Wem1 = (const float*)d_in[18];
  const float* bem1 = (const float*)d_in[19];
  const float* Wem2 = (const float*)d_in[20];
  const float* bem2 = (const float*)d_in[21];
  const float* Wec1 = (const float*)d_in[22];
  const float* bec1 = (const float*)d_in[23];
  const float* Wec2 = (const float*)d_in[24];
  const float* bec2 = (const float*)d_in[25];
  const float* Wh1 = (const float*)d_in[26];
  const float* bh1 = (const float*)d_in[27];
  const float* Wh2 = (const float*)d_in[28];
  const float* bh2 = (const float*)d_in[29];

  const int* rowi = eidx;
  const int* coli = eidx + N_EDGES;

  float* hbuf = (float*)d_out;
  float* xbuf = hbuf + (size_t)N_NODES*HDIM;
  float* epsb = xbuf + (size_t)N_NODES*3;

  char* wp = (char*)d_ws;
  auto alloc = [&](size_t bytes)->char*{
    char* p = wp; wp += (bytes + 255) & ~(size_t)255; return p;
  };
  unsigned short* WembT = (unsigned short*)alloc((size_t)128*64*2);
  unsigned short *Wn1T[NLAYERS], *Wn2T[NLAYERS];
  for (int i=0;i<NLAYERS;++i){
    Wn1T[i] = (unsigned short*)alloc((size_t)128*256*2);
    Wn2T[i] = (unsigned short*)alloc((size_t)128*128*2);
  }
  unsigned short* Wh1T  = (unsigned short*)alloc((size_t)128*128*2);
  unsigned short* blobL = (unsigned short*)alloc((size_t)NLAYERS*16*4096*2);
  unsigned short* blobE = (unsigned short*)alloc((size_t)16*4096*2);
  unsigned short* hb    = (unsigned short*)alloc((size_t)N_NODES*HDIM*2);
  int* degi   = (int*)alloc((size_t)N_NODES*4);
  int* offv   = (int*)alloc((size_t)N_NODES*4);
  int* cursor = (int*)alloc((size_t)N_NODES*4);
  int* bsum   = (int*)alloc(4096);
  float* cu   = (float*)alloc((size_t)N_NODES*3*4);
  int* rowS   = (int*)alloc((size_t)N_EDGES*4);
  int* colS   = (int*)alloc((size_t)N_EDGES*4);
  unsigned short* m_buf = (unsigned short*)alloc((size_t)N_EDGES*HDIM*2);

  // fused weight transposes (1 launch)
  ConvJobs cj;
  cj.j[0] = {W_emb, WembT, 6};
  for (int i=0;i<NLAYERS;++i){
    cj.j[1+i] = {Wn1 + (size_t)i*256*128, Wn1T[i], 8};
    cj.j[4+i] = {Wn2 + (size_t)i*128*128, Wn2T[i], 7};
  }
  cj.j[7] = {Wh1, Wh1T, 7};
  k_conv8<<<dim3(128,8), dim3(256), 0, stream>>>(cj);

  // fused blob builds (1 launch)
  BlobJobs bj;
  for (int i=0;i<NLAYERS;++i)
    bj.j[i] = {Wm1 + (size_t)i*257*128, Wm2 + (size_t)i*128*128,
               Wc1 + (size_t)i*128*128, blobL + (size_t)i*16*4096};
  bj.j[3] = {Wem1, Wem2, Wec1, blobE};
  k_blob4<<<dim3(256,4), dim3(256), 0, stream>>>(bj);

  // fused init (zero degi/cu/epsb + x copy)
  k_init<<<dim3((N_NODES*3+255)/256), dim3(256), 0, stream>>>(x_in, xbuf, cu, epsb, degi);

  k_degree<<<dim3((N_EDGES+255)/256), dim3(256), 0, stream>>>(coli, degi);
  const int nb = (N_NODES + 255)/256;
  k_scanA<<<dim3(nb), dim3(256), 0, stream>>>(degi, offv, bsum);
  k_scanB<<<dim3(1), dim3(256), 0, stream>>>(bsum, nb);
  k_scanC<<<dim3(nb), dim3(256), 0, stream>>>(offv, bsum, cursor);
  k_fill<<<dim3((N_EDGES+255)/256), dim3(256), 0, stream>>>(rowi, coli, cursor, rowS, colS);

  k_embed<<<dim3((N_NODES+63)/64), dim3(256), 0, stream>>>(h_in, WembT, b_emb, hbuf, hb);

  for (int i=0;i<NLAYERS;++i){
    const unsigned short* blob_i = blobL + (size_t)i*16*4096;
    const float* wm1r = Wm1 + (size_t)i*257*128 + (size_t)256*128;
    k_edge_mlp<<<dim3(N_EDGES/512), dim3(1024), 0, stream>>>(
      hb, xbuf, rowS, colS, blob_i,
      bm1 + i*128, wm1r, bm2 + i*128, bc1 + i*128, Wc2 + i*128,
      m_buf, cu);
    k_node_mlp<<<dim3((N_NODES+63)/64), dim3(256), 0, stream>>>(
      hbuf, hb, xbuf, m_buf, offv, degi, cu,
      Wn1T[i], bn1 + i*128, Wn2T[i], bn2 + i*128, lng + i*128, lnb + i*128);
  }
  k_eps_edge<<<dim3(N_EDGES/512), dim3(1024), 0, stream>>>(
    hb, xbuf, rowS, colS, blobE,
    bem1, Wem1 + (size_t)256*128, bem2, bec1, Wec2, bec2, epsb);
  k_eps_node<<<dim3((N_NODES+63)/64), dim3(256), 0, stream>>>(
    hbuf, xbuf, Wh1T, bh1, Wh1 + (size_t)128*128, Wh2, bh2, epsb);
}